// Round 10
// baseline (526.610 us; speedup 1.0000x reference)
//
#include <hip/hip_runtime.h>

#define T_TOK 1024
#define D_DIM 2048
#define E_NUM 32
#define F_DIM 768
#define K_TOP 8

typedef __bf16 v8bf __attribute__((ext_vector_type(8)));
typedef float v4f __attribute__((ext_vector_type(4)));
typedef unsigned short v8us __attribute__((ext_vector_type(8)));

__device__ __forceinline__ unsigned short f2b(float f) {
  unsigned int u = __builtin_bit_cast(unsigned int, f);
  u += 0x7fffu + ((u >> 16) & 1u);   // RNE
  return (unsigned short)(u >> 16);
}
__device__ __forceinline__ float b2f(unsigned short s) {
  return __builtin_bit_cast(float, (unsigned int)s << 16);
}
__device__ __forceinline__ v8us cvt8u(v4f a, v4f b) {
  v8bf r;
  r[0] = (__bf16)a[0]; r[1] = (__bf16)a[1]; r[2] = (__bf16)a[2]; r[3] = (__bf16)a[3];
  r[4] = (__bf16)b[0]; r[5] = (__bf16)b[1]; r[6] = (__bf16)b[2]; r[7] = (__bf16)b[3];
  return __builtin_bit_cast(v8us, r);
}
__device__ __forceinline__ void gload16(const void* g, void* l) {
  __builtin_amdgcn_global_load_lds(
      (const __attribute__((address_space(1))) void*)g,
      (__attribute__((address_space(3))) void*)l, 16, 0, 0);
}
// count-exact VMEM load (exactly one global_load_dwordx4)
__device__ __forceinline__ v4f gload4f(const char* p) {
  v4f r;
  asm volatile("global_load_dwordx4 %0, %1, off" : "=v"(r) : "v"(p));
  return r;
}

#define VMWAIT(N) asm volatile("s_waitcnt vmcnt(" #N ")" ::: "memory")
#define LGKM0() asm volatile("s_waitcnt lgkmcnt(0)" ::: "memory")
#define SBAR() __builtin_amdgcn_s_barrier()
#define SCHEDB() __builtin_amdgcn_sched_barrier(0)

// ---------------- Router: logits (fp32), top-8, bucket, x->bf16 ----------------
__global__ __launch_bounds__(256) void router_kernel(
    const float* __restrict__ x, const float* __restrict__ gw,
    unsigned short* __restrict__ xb, int* __restrict__ counts,
    int* __restrict__ tlist, int* __restrict__ topk_e, int* __restrict__ topk_p,
    float* __restrict__ topk_w, float* __restrict__ wlist)
{
  const int t = blockIdx.x, tid = threadIdx.x;
  const float* xr = x + (size_t)t * D_DIM;

  {
    v4f f0 = *reinterpret_cast<const v4f*>(xr + tid * 8);
    v4f f1 = *reinterpret_cast<const v4f*>(xr + tid * 8 + 4);
    *reinterpret_cast<v8us*>(xb + (size_t)t * D_DIM + tid * 8) = cvt8u(f0, f1);
  }

  __shared__ float logits[E_NUM];
  const int lane = tid & 63, wave = tid >> 6;
  for (int j = 0; j < 8; ++j) {
    int e = wave * 8 + j;
    const float* wr = gw + (size_t)e * D_DIM;
    float s = 0.f;
#pragma unroll
    for (int i = 0; i < D_DIM / 64; ++i) s = fmaf(xr[lane + i * 64], wr[lane + i * 64], s);
#pragma unroll
    for (int off = 32; off > 0; off >>= 1) s += __shfl_xor(s, off);
    if (lane == 0) logits[e] = s;
  }
  __syncthreads();

  if (tid == 0) {
    float lg[E_NUM];
#pragma unroll
    for (int e2 = 0; e2 < E_NUM; ++e2) lg[e2] = logits[e2];
    int sel[K_TOP]; float sv[K_TOP];
    for (int k = 0; k < K_TOP; ++k) {
      int best = 0; float bv = -3.4e38f;
      for (int e2 = 0; e2 < E_NUM; ++e2)
        if (lg[e2] > bv) { bv = lg[e2]; best = e2; }
      sel[k] = best; sv[k] = bv; lg[best] = -3.4e38f;
    }
    float mx = sv[0], s8 = 0.f, ww[K_TOP];
    for (int k = 0; k < K_TOP; ++k) { ww[k] = __expf(sv[k] - mx); s8 += ww[k]; }
    float inv = 1.f / s8;
    for (int k = 0; k < K_TOP; ++k) {
      float w = ww[k] * inv;
      int e2 = sel[k];
      int pos = atomicAdd(&counts[e2], 1);
      tlist[e2 * T_TOK + pos] = t;
      wlist[e2 * T_TOK + pos] = w;
      topk_e[t * K_TOP + k] = e2;
      topk_p[t * K_TOP + k] = pos;
      topk_w[t * K_TOP + k] = w;
    }
  }
}

__global__ void scan_kernel(const int* __restrict__ counts, int* __restrict__ offsets)
{
  if (threadIdx.x == 0) {
    int run = 0;
    for (int e = 0; e < E_NUM; ++e) { offsets[e] = run; run += counts[e]; }
  }
}

// ---------------- Gate+Up grouped GEMM: block=(e,tf), M-loop inside ----------------
// 512 thr (8 waves, 4M x 2N). BN=96 (both g & u), M = up to 2 tiles of 192, groupK=64.
// B read ONCE per k-group for both M-tiles (the round-9 duplication fix).
// LDS 144KB: A dbuf 2x48KB @0 (2 tm x 192rows x 128B); B dbuf 2x24KB @98304
// (Bg 12KB + Bu 12KB, bf16, XOR-swizzled).  Grid 8x32 = 256 blocks = 1/CU.
// Pipeline (r9): per group: VMWAIT(6) [B regs]; write B; issue B' (6 asm) + A'
// (6 gload_lds); VMWAIT(12) [A landed]; LGKM0; SBAR; MFMA both tm; SBAR.
__global__ __launch_bounds__(512, 1) void gateup_kernel(
    const unsigned short* __restrict__ xb, const float* __restrict__ wg,
    const float* __restrict__ wu, const int* __restrict__ counts,
    const int* __restrict__ offsets, const int* __restrict__ tlist,
    unsigned short* __restrict__ hbuf)
{
  const int e = blockIdx.y;
  const int cnt = counts[e];
  const int tf = blockIdx.x;           // 0..7 (96-wide F tiles)
  const bool two = cnt > 192;

  __shared__ __align__(16) unsigned char lds[147456];

  const int tid = threadIdx.x;
  const int lane = tid & 63;
  const int wave = tid >> 6;
  const int wm = wave >> 1;  // 0..3 (48 rows each)
  const int wn = wave & 1;   // 0..1 (48 cols each)
  const int l15 = lane & 15;
  const int l4 = lane >> 4;

  // ---- A staging: 6 slots/thread = 2 tm x 192 rows x 8 granules, src-swizzled ----
  const char* xbB = (const char*)xb;
  const int gl = tid & 7;
  unsigned asrc[6];
#pragma unroll
  for (int c = 0; c < 6; ++c) {
    int rp = (tid >> 3) + c * 64;        // 0..383
    int row = rp % 192;                  // row within tile
    int tm = rp / 192;
    int rg = tm * 192 + row;
    if (rg > cnt - 1) rg = cnt - 1;
    int tok = tlist[e * T_TOK + rg];
    int gg = gl ^ (row & 7);
    asrc[c] = (unsigned)tok * 4096u + (unsigned)(gg * 16);
  }
  const unsigned adst0 = (unsigned)(tid * 16);   // + c*8192 linear

  // ---- B staging: 3 pair-slots/thread over {g:768, u:768} pairs of 32B fp32 ----
  const char* gB = (const char*)wg + (size_t)e * F_DIM * D_DIM * 4;
  const char* uB = (const char*)wu + (size_t)e * F_DIM * D_DIM * 4;
  const char* bp[3];
  unsigned bdst[3];
#pragma unroll
  for (int c = 0; c < 3; ++c) {
    int idx = tid + c * 512;             // 0..1535
    int mat = idx >= 768;
    int mi = mat ? idx - 768 : idx;
    int row = mi >> 3, pr = mi & 7;
    bp[c] = (mat ? uB : gB) + (size_t)(tf * 96 + row) * 8192 + pr * 32;
    bdst[c] = (unsigned)(mat * 12288 + row * 128 + ((pr ^ (row & 7)) * 16));
  }

  // ---- read addresses ----
  unsigned aRd[3];
#pragma unroll
  for (int fm = 0; fm < 3; ++fm) {
    int row = wm * 48 + fm * 16 + l15;
    aRd[fm] = (unsigned)(row * 128 + ((l4 ^ (row & 7)) * 16));
  }
  unsigned bRd[3];
#pragma unroll
  for (int fn = 0; fn < 3; ++fn) {
    int row = wn * 48 + fn * 16 + l15;
    bRd[fn] = (unsigned)(row * 128 + ((l4 ^ (row & 7)) * 16));
  }

  v4f zero = {0.f, 0.f, 0.f, 0.f};
  v4f accg[2][3][3], accu[2][3][3];
#pragma unroll
  for (int tm = 0; tm < 2; ++tm)
#pragma unroll
    for (int fm = 0; fm < 3; ++fm)
#pragma unroll
      for (int fn = 0; fn < 3; ++fn) { accg[tm][fm][fn] = zero; accu[tm][fm][fn] = zero; }

  auto COMPUTE = [&](int tm, unsigned ab, unsigned bb, unsigned sx) {
    v8bf af[3], bg[3], bu[3];
    const unsigned at = ab + (unsigned)tm * 24576u;
#pragma unroll
    for (int fm = 0; fm < 3; ++fm)
      af[fm] = __builtin_bit_cast(v8bf,
          *reinterpret_cast<const v8us*>(&lds[at + (aRd[fm] ^ sx)]));
#pragma unroll
    for (int fn = 0; fn < 3; ++fn) {
      bg[fn] = __builtin_bit_cast(v8bf,
          *reinterpret_cast<const v8us*>(&lds[bb + (bRd[fn] ^ sx)]));
      bu[fn] = __builtin_bit_cast(v8bf,
          *reinterpret_cast<const v8us*>(&lds[bb + 12288u + (bRd[fn] ^ sx)]));
    }
#pragma unroll
    for (int fm = 0; fm < 3; ++fm)
#pragma unroll
      for (int fn = 0; fn < 3; ++fn) {
        accg[tm][fm][fn] = __builtin_amdgcn_mfma_f32_16x16x32_bf16(af[fm], bg[fn], accg[tm][fm][fn], 0, 0, 0);
        accu[tm][fm][fn] = __builtin_amdgcn_mfma_f32_16x16x32_bf16(af[fm], bu[fn], accu[tm][fm][fn], 0, 0, 0);
      }
  };

  const int NG = D_DIM / 64;  // 32

  // prologue: group 0 -> queue [B0 x6, A0 x6]
  v4f b0[3], b1[3];
#pragma unroll
  for (int c = 0; c < 3; ++c) { b0[c] = gload4f(bp[c]); b1[c] = gload4f(bp[c] + 16); }
  SCHEDB();
#pragma unroll
  for (int c = 0; c < 6; ++c) gload16(xbB + asrc[c], &lds[adst0 + c * 8192u]);
  SCHEDB();

#pragma unroll 2
  for (int i = 0; i < NG; ++i) {
    const unsigned ab = (unsigned)(i & 1) * 49152u;
    const unsigned bb = 98304u + (unsigned)(i & 1) * 24576u;
    VMWAIT(6); SCHEDB();   // B(i) regs landed; A(i) x6 still in flight
#pragma unroll
    for (int c = 0; c < 3; ++c)
      *reinterpret_cast<v8us*>(&lds[bb + bdst[c]]) = cvt8u(b0[c], b1[c]);
    if (i + 1 < NG) {
      const unsigned an = (unsigned)((i + 1) & 1) * 49152u;
      const unsigned ko = (unsigned)(i + 1) * 256u;
#pragma unroll
      for (int c = 0; c < 3; ++c) { b0[c] = gload4f(bp[c] + ko); b1[c] = gload4f(bp[c] + ko + 16); }
      SCHEDB();
      const unsigned ao = (unsigned)(i + 1) * 128u;
#pragma unroll
      for (int c = 0; c < 6; ++c) gload16(xbB + asrc[c] + ao, &lds[an + adst0 + c * 8192u]);
      SCHEDB();
      VMWAIT(12);  // queue [A(i)6, B(i+1)6, A(i+1)6] -> drain A(i)
    } else {
      VMWAIT(0);
    }
    SCHEDB(); LGKM0(); SBAR(); SCHEDB();
    COMPUTE(0, ab, bb, 0u);
    COMPUTE(0, ab, bb, 64u);
    if (two) {
      COMPUTE(1, ab, bb, 0u);
      COMPUTE(1, ab, bb, 64u);
    }
    SCHEDB(); SBAR();
  }

  const int off_e = offsets[e];
#pragma unroll
  for (int tm = 0; tm < 2; ++tm)
#pragma unroll
    for (int fm = 0; fm < 3; ++fm)
#pragma unroll
      for (int fn = 0; fn < 3; ++fn)
#pragma unroll
        for (int i = 0; i < 4; ++i) {
          int rg = tm * 192 + wm * 48 + fm * 16 + l4 * 4 + i;
          if (rg < cnt) {
            int col = tf * 96 + wn * 48 + fn * 16 + l15;
            float g = accg[tm][fm][fn][i];
            float uu = accu[tm][fm][fn][i];
            float h = g * (1.f / (1.f + __expf(-g))) * uu;
            hbuf[(size_t)(off_e + rg) * F_DIM + col] = f2b(h);
          }
        }
}

// ---------------- Down grouped GEMM: block=(e,td), M-loop inside ----------------
// BN=128, M = up to 2 tiles of 192, groupK=64, NG=12. Grid 16x32 = 512 blocks.
// LDS 128KB: A dbuf 2x48KB @0; B bf16 dbuf 2x16KB @98304.
// Pipeline: 4 asm B + 6 gload_lds per group; VMWAIT(6) / VMWAIT(10).
template <int STAGEOUT>
__global__ __launch_bounds__(512, 1) void down_kernel(
    const unsigned short* __restrict__ hbuf, const float* __restrict__ wd,
    const int* __restrict__ counts, const int* __restrict__ offsets,
    const int* __restrict__ tlist, const float* __restrict__ wlist,
    unsigned short* __restrict__ ybuf, float* __restrict__ out)
{
  const int e = blockIdx.y;
  const int cnt = counts[e];
  const int td = blockIdx.x;           // 0..15 (128-wide D tiles)
  const bool two = cnt > 192;
  const int off_e = offsets[e];

  __shared__ __align__(16) unsigned char lds[131072];

  const int tid = threadIdx.x;
  const int lane = tid & 63;
  const int wave = tid >> 6;
  const int wm = wave >> 1;  // 0..3 (48 rows)
  const int wn = wave & 1;   // 0..1 (64 cols)
  const int l15 = lane & 15;
  const int l4 = lane >> 4;

  const char* hB = (const char*)hbuf;
  const int gl = tid & 7;
  unsigned asrc[6];
#pragma unroll
  for (int c = 0; c < 6; ++c) {
    int rp = (tid >> 3) + c * 64;
    int row = rp % 192;
    int tm = rp / 192;
    int rg = tm * 192 + row;
    if (rg > cnt - 1) rg = cnt - 1;
    int gg = gl ^ (row & 7);
    asrc[c] = (unsigned)(off_e + rg) * 1536u + (unsigned)(gg * 16);
  }
  const unsigned adst0 = (unsigned)(tid * 16);

  // B staging: 2 pair-slots/thread over 128 rows x 8 pairs (32B fp32 each)
  const char* bB = (const char*)wd + (size_t)e * D_DIM * F_DIM * 4;
  const char* bp[2];
  unsigned bdst[2];
#pragma unroll
  for (int c = 0; c < 2; ++c) {
    int idx = tid + c * 512;             // 0..1023
    int row = idx >> 3, pr = idx & 7;
    bp[c] = bB + (size_t)(td * 128 + row) * 3072 + pr * 32;
    bdst[c] = (unsigned)(row * 128 + ((pr ^ (row & 7)) * 16));
  }

  unsigned aRd[3];
#pragma unroll
  for (int fm = 0; fm < 3; ++fm) {
    int row = wm * 48 + fm * 16 + l15;
    aRd[fm] = (unsigned)(row * 128 + ((l4 ^ (row & 7)) * 16));
  }
  unsigned bRd[4];
#pragma unroll
  for (int fn = 0; fn < 4; ++fn) {
    int row = wn * 64 + fn * 16 + l15;
    bRd[fn] = (unsigned)(row * 128 + ((l4 ^ (row & 7)) * 16));
  }

  v4f zero = {0.f, 0.f, 0.f, 0.f};
  v4f acc[2][3][4];
#pragma unroll
  for (int tm = 0; tm < 2; ++tm)
#pragma unroll
    for (int fm = 0; fm < 3; ++fm)
#pragma unroll
      for (int fn = 0; fn < 4; ++fn) acc[tm][fm][fn] = zero;

  auto COMPUTE = [&](int tm, unsigned ab, unsigned bb, unsigned sx) {
    v8bf af[3], bf_[4];
    const unsigned at = ab + (unsigned)tm * 24576u;
#pragma unroll
    for (int fm = 0; fm < 3; ++fm)
      af[fm] = __builtin_bit_cast(v8bf,
          *reinterpret_cast<const v8us*>(&lds[at + (aRd[fm] ^ sx)]));
#pragma unroll
    for (int fn = 0; fn < 4; ++fn)
      bf_[fn] = __builtin_bit_cast(v8bf,
          *reinterpret_cast<const v8us*>(&lds[bb + (bRd[fn] ^ sx)]));
#pragma unroll
    for (int fm = 0; fm < 3; ++fm)
#pragma unroll
      for (int fn = 0; fn < 4; ++fn)
        acc[tm][fm][fn] = __builtin_amdgcn_mfma_f32_16x16x32_bf16(af[fm], bf_[fn], acc[tm][fm][fn], 0, 0, 0);
  };

  const int NG = F_DIM / 64;  // 12

  v4f b0[2], b1[2];
#pragma unroll
  for (int c = 0; c < 2; ++c) { b0[c] = gload4f(bp[c]); b1[c] = gload4f(bp[c] + 16); }
  SCHEDB();
#pragma unroll
  for (int c = 0; c < 6; ++c) gload16(hB + asrc[c], &lds[adst0 + c * 8192u]);
  SCHEDB();

#pragma unroll 2
  for (int i = 0; i < NG; ++i) {
    const unsigned ab = (unsigned)(i & 1) * 49152u;
    const unsigned bb = 98304u + (unsigned)(i & 1) * 16384u;
    VMWAIT(6); SCHEDB();   // B(i) x4 landed; A(i) x6 in flight
#pragma unroll
    for (int c = 0; c < 2; ++c)
      *reinterpret_cast<v8us*>(&lds[bb + bdst[c]]) = cvt8u(b0[c], b1[c]);
    if (i + 1 < NG) {
      const unsigned an = (unsigned)((i + 1) & 1) * 49152u;
      const unsigned ko = (unsigned)(i + 1) * 256u;
#pragma unroll
      for (int c = 0; c < 2; ++c) { b0[c] = gload4f(bp[c] + ko); b1[c] = gload4f(bp[c] + ko + 16); }
      SCHEDB();
      const unsigned ao = (unsigned)(i + 1) * 128u;
#pragma unroll
      for (int c = 0; c < 6; ++c) gload16(hB + asrc[c] + ao, &lds[an + adst0 + c * 8192u]);
      SCHEDB();
      VMWAIT(10);  // queue [A(i)6, B(i+1)4, A(i+1)6] -> drain A(i)
    } else {
      VMWAIT(0);
    }
    SCHEDB(); LGKM0(); SBAR(); SCHEDB();
    COMPUTE(0, ab, bb, 0u);
    COMPUTE(0, ab, bb, 64u);
    if (two) {
      COMPUTE(1, ab, bb, 0u);
      COMPUTE(1, ab, bb, 64u);
    }
    SCHEDB(); SBAR();
  }

#pragma unroll
  for (int tm = 0; tm < 2; ++tm)
#pragma unroll
    for (int fm = 0; fm < 3; ++fm)
#pragma unroll
      for (int fn = 0; fn < 4; ++fn)
#pragma unroll
        for (int i = 0; i < 4; ++i) {
          int rg = tm * 192 + wm * 48 + fm * 16 + l4 * 4 + i;
          if (rg < cnt) {
            int col = td * 128 + wn * 64 + fn * 16 + l15;
            float y = acc[tm][fm][fn][i];
            if (STAGEOUT) {
              ybuf[(size_t)(off_e + rg) * D_DIM + col] = f2b(y);
            } else {
              int tok = tlist[e * T_TOK + rg];
              float w = wlist[e * T_TOK + rg];
              atomicAdd(out + (size_t)tok * D_DIM + col, w * y);
            }
          }
        }
}

// ---------------- Combine: out[t] = sum_k w_k * y[slot_k] ----------------
__global__ __launch_bounds__(256) void combine_kernel(
    const unsigned short* __restrict__ ybuf, const int* __restrict__ topk_e,
    const int* __restrict__ topk_p, const float* __restrict__ topk_w,
    const int* __restrict__ offsets, float* __restrict__ out)
{
  const int t = blockIdx.x, tid = threadIdx.x;
  const int d0 = tid * 8;
  float acc[8] = {0.f, 0.f, 0.f, 0.f, 0.f, 0.f, 0.f, 0.f};
#pragma unroll
  for (int k = 0; k < K_TOP; ++k) {
    int e = topk_e[t * K_TOP + k];
    int slot = offsets[e] + topk_p[t * K_TOP + k];
    float w = topk_w[t * K_TOP + k];
    v8us v = *reinterpret_cast<const v8us*>(ybuf + (size_t)slot * D_DIM + d0);
#pragma unroll
    for (int j = 0; j < 8; ++j) acc[j] += w * b2f(v[j]);
  }
  v4f o0 = {acc[0], acc[1], acc[2], acc[3]};
  v4f o1 = {acc[4], acc[5], acc[6], acc[7]};
  *reinterpret_cast<v4f*>(out + (size_t)t * D_DIM + d0) = o0;
  *reinterpret_cast<v4f*>(out + (size_t)t * D_DIM + d0 + 4) = o1;
}

extern "C" void kernel_launch(void* const* d_in, const int* in_sizes, int n_in,
                              void* d_out, int out_size, void* d_ws, size_t ws_size,
                              hipStream_t stream)
{
  const float* x  = (const float*)d_in[0];
  const float* gw = (const float*)d_in[1];
  const float* wg = (const float*)d_in[2];
  const float* wu = (const float*)d_in[3];
  const float* wd = (const float*)d_in[4];
  float* out = (float*)d_out;

  char* p = (char*)d_ws;
  auto alloc = [&](size_t bytes) {
    char* r = p;
    p += (bytes + 255) & ~(size_t)255;
    return r;
  };
  int* counts   = (int*)alloc(E_NUM * 4);
  int* offsets  = (int*)alloc(E_NUM * 4);
  int* tlist    = (int*)alloc((size_t)E_NUM * T_TOK * 4);
  float* wlist  = (float*)alloc((size_t)E_NUM * T_TOK * 4);
  int* topk_e   = (int*)alloc((size_t)T_TOK * K_TOP * 4);
  int* topk_p   = (int*)alloc((size_t)T_TOK * K_TOP * 4);
  float* topk_w = (float*)alloc((size_t)T_TOK * K_TOP * 4);
  unsigned short* xb   = (unsigned short*)alloc((size_t)T_TOK * D_DIM * 2);
  unsigned short* hbuf = (unsigned short*)alloc((size_t)T_TOK * K_TOP * F_DIM * 2);
  size_t need_atomic = (size_t)(p - (char*)d_ws);
  unsigned short* ybuf = (unsigned short*)alloc((size_t)T_TOK * K_TOP * D_DIM * 2);
  size_t need_stage = (size_t)(p - (char*)d_ws);

  if (ws_size < need_atomic) return;
  const bool stage = (ws_size >= need_stage);

  hipMemsetAsync(counts, 0, E_NUM * 4, stream);
  router_kernel<<<T_TOK, 256, 0, stream>>>(x, gw, xb, counts, tlist, topk_e, topk_p, topk_w, wlist);
  scan_kernel<<<1, 64, 0, stream>>>(counts, offsets);
  gateup_kernel<<<dim3(8, E_NUM), 512, 0, stream>>>(
      xb, wg, wu, counts, offsets, tlist, hbuf);
  if (stage) {
    down_kernel<1><<<dim3(16, E_NUM), 512, 0, stream>>>(
        hbuf, wd, counts, offsets, tlist, wlist, ybuf, out);
    combine_kernel<<<T_TOK, 256, 0, stream>>>(ybuf, topk_e, topk_p, topk_w, offsets, out);
  } else {
    hipMemsetAsync(out, 0, (size_t)out_size * 4, stream);
    down_kernel<0><<<dim3(16, E_NUM), 512, 0, stream>>>(
        hbuf, wd, counts, offsets, tlist, wlist, ybuf, out);
  }
}

// Round 11
// 265.796 us; speedup vs baseline: 1.9813x; 1.9813x over previous
//
#include <hip/hip_runtime.h>

#define T_TOK 1024
#define D_DIM 2048
#define E_NUM 32
#define F_DIM 768
#define K_TOP 8

typedef __bf16 v8bf __attribute__((ext_vector_type(8)));
typedef float v4f __attribute__((ext_vector_type(4)));
typedef unsigned short v8us __attribute__((ext_vector_type(8)));

__device__ __forceinline__ unsigned short f2b(float f) {
  unsigned int u = __builtin_bit_cast(unsigned int, f);
  u += 0x7fffu + ((u >> 16) & 1u);   // RNE
  return (unsigned short)(u >> 16);
}
__device__ __forceinline__ float b2f(unsigned short s) {
  return __builtin_bit_cast(float, (unsigned int)s << 16);
}
__device__ __forceinline__ v8us cvt8u(v4f a, v4f b) {
  v8bf r;
  r[0] = (__bf16)a[0]; r[1] = (__bf16)a[1]; r[2] = (__bf16)a[2]; r[3] = (__bf16)a[3];
  r[4] = (__bf16)b[0]; r[5] = (__bf16)b[1]; r[6] = (__bf16)b[2]; r[7] = (__bf16)b[3];
  return __builtin_bit_cast(v8us, r);
}
__device__ __forceinline__ void gload16(const void* g, void* l) {
  __builtin_amdgcn_global_load_lds(
      (const __attribute__((address_space(1))) void*)g,
      (__attribute__((address_space(3))) void*)l, 16, 0, 0);
}
// count-exact VMEM load (exactly one global_load_dwordx4)
__device__ __forceinline__ v4f gload4f(const char* p) {
  v4f r;
  asm volatile("global_load_dwordx4 %0, %1, off" : "=v"(r) : "v"(p));
  return r;
}

#define VMWAIT(N) asm volatile("s_waitcnt vmcnt(" #N ")" ::: "memory")
#define LGKM0() asm volatile("s_waitcnt lgkmcnt(0)" ::: "memory")
#define SBAR() __builtin_amdgcn_s_barrier()
#define SCHEDB() __builtin_amdgcn_sched_barrier(0)

// ---------------- Router: logits (fp32), top-8, bucket, x->bf16 ----------------
__global__ __launch_bounds__(256) void router_kernel(
    const float* __restrict__ x, const float* __restrict__ gw,
    unsigned short* __restrict__ xb, int* __restrict__ counts,
    int* __restrict__ tlist, int* __restrict__ topk_e, int* __restrict__ topk_p,
    float* __restrict__ topk_w, float* __restrict__ wlist)
{
  const int t = blockIdx.x, tid = threadIdx.x;
  const float* xr = x + (size_t)t * D_DIM;

  {
    v4f f0 = *reinterpret_cast<const v4f*>(xr + tid * 8);
    v4f f1 = *reinterpret_cast<const v4f*>(xr + tid * 8 + 4);
    *reinterpret_cast<v8us*>(xb + (size_t)t * D_DIM + tid * 8) = cvt8u(f0, f1);
  }

  __shared__ float logits[E_NUM];
  const int lane = tid & 63, wave = tid >> 6;
  for (int j = 0; j < 8; ++j) {
    int e = wave * 8 + j;
    const float* wr = gw + (size_t)e * D_DIM;
    float s = 0.f;
#pragma unroll
    for (int i = 0; i < D_DIM / 64; ++i) s = fmaf(xr[lane + i * 64], wr[lane + i * 64], s);
#pragma unroll
    for (int off = 32; off > 0; off >>= 1) s += __shfl_xor(s, off);
    if (lane == 0) logits[e] = s;
  }
  __syncthreads();

  if (tid == 0) {
    float lg[E_NUM];
#pragma unroll
    for (int e2 = 0; e2 < E_NUM; ++e2) lg[e2] = logits[e2];
    int sel[K_TOP]; float sv[K_TOP];
    for (int k = 0; k < K_TOP; ++k) {
      int best = 0; float bv = -3.4e38f;
      for (int e2 = 0; e2 < E_NUM; ++e2)
        if (lg[e2] > bv) { bv = lg[e2]; best = e2; }
      sel[k] = best; sv[k] = bv; lg[best] = -3.4e38f;
    }
    float mx = sv[0], s8 = 0.f, ww[K_TOP];
    for (int k = 0; k < K_TOP; ++k) { ww[k] = __expf(sv[k] - mx); s8 += ww[k]; }
    float inv = 1.f / s8;
    for (int k = 0; k < K_TOP; ++k) {
      float w = ww[k] * inv;
      int e2 = sel[k];
      int pos = atomicAdd(&counts[e2], 1);
      tlist[e2 * T_TOK + pos] = t;
      wlist[e2 * T_TOK + pos] = w;
      topk_e[t * K_TOP + k] = e2;
      topk_p[t * K_TOP + k] = pos;
      topk_w[t * K_TOP + k] = w;
    }
  }
}

__global__ void scan_kernel(const int* __restrict__ counts, int* __restrict__ offsets)
{
  if (threadIdx.x == 0) {
    int run = 0;
    for (int e = 0; e < E_NUM; ++e) { offsets[e] = run; run += counts[e]; }
  }
}

// ---------------- Gate+Up grouped GEMM, counted-vmcnt pipeline (r9 layout) ------
// XCD-aware block mapping: all 24 blocks (12 tf x 2 tm) of expert e are placed on
// XCD e%8 (dispatch round-robin: XCD = blockIdx.x % 8), so the expert's A and B
// panel re-reads hit that XCD's L2 instead of re-fetching from L3.
// 512 thr (8 waves, 4M x 2N). BM=192, BN=64 (g & u), groupK=64, NG=32.
// A (bf16 xb): 128B/row via global_load_lds (src XOR-swizzled), dbuf 2x24KB @0.
// B (fp32 wg/wu): asm global_load_dwordx4 (count-exact) -> cvt -> bf16 LDS,
//   dbuf @49152, 2x16KB. Total LDS 80KB.
__global__ __launch_bounds__(512, 4) void gateup_kernel(
    const unsigned short* __restrict__ xb, const float* __restrict__ wg,
    const float* __restrict__ wu, const int* __restrict__ counts,
    const int* __restrict__ offsets, const int* __restrict__ tlist,
    unsigned short* __restrict__ hbuf)
{
  // id = xcd + 8*j ; j = (e/8)*24 + tf*2 + tm ; xcd = e%8
  const int bid = blockIdx.x;
  const int xcd = bid & 7;
  const int j = bid >> 3;             // 0..95
  const int e = xcd + 8 * (j / 24);
  const int r = j % 24;
  const int tf = r >> 1;              // 0..11
  const int tm = r & 1;               // 0..1
  const int cnt = counts[e];
  if (tm * 192 >= cnt) return;

  __shared__ __align__(16) unsigned char lds[81920];

  const int tid = threadIdx.x;
  const int lane = tid & 63;
  const int wave = tid >> 6;
  const int wm = wave >> 1;  // 0..3 (48 rows)
  const int wn = wave & 1;   // 0..1 (32 cols)
  const int l15 = lane & 15;
  const int l4 = lane >> 4;

  // ---- A staging: 3 slots/thread, 8x16B granules per 128B row, src-swizzled ----
  const char* xbB = (const char*)xb;
  unsigned asrc[3], adst[3];
#pragma unroll
  for (int c = 0; c < 3; ++c) {
    int idx = tid + c * 512;        // 0..1535
    int rr = idx >> 3, gl = idx & 7;
    int rg = tm * 192 + rr;
    if (rg > cnt - 1) rg = cnt - 1;
    int tok = tlist[e * T_TOK + rg];
    int gg = gl ^ (rr & 7);
    asrc[c] = (unsigned)tok * 4096u + (unsigned)(gg * 16);
    adst[c] = (unsigned)(idx * 16);
  }
  // ---- B staging: thread owns (row=tid>>3, granule bg8=tid&7): 32B fp32 -> 16B bf16 ----
  const int brow = tid >> 3, bg8 = tid & 7;
  const unsigned bsrc = (unsigned)((tf * 64 + brow) * 8192 + bg8 * 32);
  const unsigned bdst = (unsigned)(brow * 128 + ((bg8 ^ (brow & 7)) * 16));
  const char* gB = (const char*)wg + (size_t)e * F_DIM * D_DIM * 4;
  const char* uB = (const char*)wu + (size_t)e * F_DIM * D_DIM * 4;

  // ---- read addresses (sub-step 1 = byte XOR 64) ----
  unsigned aRd[3];
#pragma unroll
  for (int fm = 0; fm < 3; ++fm) {
    int row = wm * 48 + fm * 16 + l15;
    aRd[fm] = (unsigned)(row * 128 + ((l4 ^ (row & 7)) * 16));
  }
  unsigned bRd[2];
#pragma unroll
  for (int fn = 0; fn < 2; ++fn) {
    int row = wn * 32 + fn * 16 + l15;
    bRd[fn] = (unsigned)(row * 128 + ((l4 ^ (row & 7)) * 16));
  }

  v4f zero = {0.f, 0.f, 0.f, 0.f};
  v4f accg[3][2], accu[3][2];
#pragma unroll
  for (int fm = 0; fm < 3; ++fm)
#pragma unroll
    for (int fn = 0; fn < 2; ++fn) { accg[fm][fn] = zero; accu[fm][fn] = zero; }

  auto COMPUTE = [&](unsigned ab, unsigned bb, unsigned sx) {
    v8bf af[3], bg[2], bu[2];
#pragma unroll
    for (int fm = 0; fm < 3; ++fm)
      af[fm] = __builtin_bit_cast(v8bf,
          *reinterpret_cast<const v8us*>(&lds[ab + (aRd[fm] ^ sx)]));
#pragma unroll
    for (int fn = 0; fn < 2; ++fn) {
      bg[fn] = __builtin_bit_cast(v8bf,
          *reinterpret_cast<const v8us*>(&lds[bb + (bRd[fn] ^ sx)]));
      bu[fn] = __builtin_bit_cast(v8bf,
          *reinterpret_cast<const v8us*>(&lds[bb + 8192u + (bRd[fn] ^ sx)]));
    }
#pragma unroll
    for (int fm = 0; fm < 3; ++fm)
#pragma unroll
      for (int fn = 0; fn < 2; ++fn) {
        accg[fm][fn] = __builtin_amdgcn_mfma_f32_16x16x32_bf16(af[fm], bg[fn], accg[fm][fn], 0, 0, 0);
        accu[fm][fn] = __builtin_amdgcn_mfma_f32_16x16x32_bf16(af[fm], bu[fn], accu[fm][fn], 0, 0, 0);
      }
  };

  const int NG = D_DIM / 64;  // 32

  // prologue: group 0 -> queue [B0 x4, A0 x3]
  v4f g0 = gload4f(gB + bsrc);
  v4f g1 = gload4f(gB + bsrc + 16);
  v4f u0 = gload4f(uB + bsrc);
  v4f u1 = gload4f(uB + bsrc + 16);
  SCHEDB();
#pragma unroll
  for (int c = 0; c < 3; ++c) gload16(xbB + asrc[c], &lds[adst[c]]);
  SCHEDB();

#pragma unroll 2
  for (int i = 0; i < NG; ++i) {
    const unsigned ab = (unsigned)(i & 1) * 24576u;
    const unsigned bb = 49152u + (unsigned)(i & 1) * 16384u;
    VMWAIT(3); SCHEDB();   // B(i) regs landed; A(i) x3 still in flight
    *reinterpret_cast<v8us*>(&lds[bb + bdst]) = cvt8u(g0, g1);
    *reinterpret_cast<v8us*>(&lds[bb + 8192u + bdst]) = cvt8u(u0, u1);
    if (i + 1 < NG) {
      const unsigned an = (unsigned)((i + 1) & 1) * 24576u;
      unsigned bo = bsrc + (unsigned)(i + 1) * 256u;
      g0 = gload4f(gB + bo);
      g1 = gload4f(gB + bo + 16);
      u0 = gload4f(uB + bo);
      u1 = gload4f(uB + bo + 16);
      SCHEDB();
      unsigned ao = (unsigned)(i + 1) * 128u;
#pragma unroll
      for (int c = 0; c < 3; ++c) gload16(xbB + asrc[c] + ao, &lds[an + adst[c]]);
      SCHEDB();
      VMWAIT(7);   // queue [A(i)3, B(i+1)4, A(i+1)3] -> drain A(i); 7 stay live
    } else {
      VMWAIT(0);
    }
    SCHEDB(); LGKM0(); SBAR(); SCHEDB();
    COMPUTE(ab, bb, 0u);
    COMPUTE(ab, bb, 64u);
    SCHEDB(); SBAR();
  }

  const int off_e = offsets[e];
#pragma unroll
  for (int fm = 0; fm < 3; ++fm)
#pragma unroll
    for (int fn = 0; fn < 2; ++fn)
#pragma unroll
      for (int i = 0; i < 4; ++i) {
        int rloc = wm * 48 + fm * 16 + l4 * 4 + i;
        int rg = tm * 192 + rloc;
        if (rg < cnt) {
          int col = tf * 64 + wn * 32 + fn * 16 + l15;
          float g = accg[fm][fn][i];
          float uu = accu[fm][fn][i];
          float h = g * (1.f / (1.f + __expf(-g))) * uu;
          hbuf[(size_t)(off_e + rg) * F_DIM + col] = f2b(h);
        }
      }
}

// ---------------- Down grouped GEMM: y = h @ wd[e]^T ----------------
// XCD-aware mapping: 64 blocks (32 td x 2 tm) of expert e on XCD e%8.
// BM=192, BN=64, groupK=64, NG=12. A dbuf 2x24KB @0; B bf16 dbuf 2x8KB @49152.
template <int STAGEOUT>
__global__ __launch_bounds__(512, 4) void down_kernel(
    const unsigned short* __restrict__ hbuf, const float* __restrict__ wd,
    const int* __restrict__ counts, const int* __restrict__ offsets,
    const int* __restrict__ tlist, const float* __restrict__ wlist,
    unsigned short* __restrict__ ybuf, float* __restrict__ out)
{
  // id = xcd + 8*j ; j = (e/8)*64 + td*2 + tm ; xcd = e%8
  const int bid = blockIdx.x;
  const int xcd = bid & 7;
  const int j = bid >> 3;             // 0..255
  const int e = xcd + 8 * (j / 64);
  const int r = j % 64;
  const int td = r >> 1;              // 0..31
  const int tm = r & 1;               // 0..1
  const int cnt = counts[e];
  if (tm * 192 >= cnt) return;
  const int off_e = offsets[e];

  __shared__ __align__(16) unsigned char lds[65536];

  const int tid = threadIdx.x;
  const int lane = tid & 63;
  const int wave = tid >> 6;
  const int wm = wave >> 1;
  const int wn = wave & 1;
  const int l15 = lane & 15;
  const int l4 = lane >> 4;

  const char* hB = (const char*)hbuf;
  unsigned asrc[3], adst[3];
#pragma unroll
  for (int c = 0; c < 3; ++c) {
    int idx = tid + c * 512;
    int rr = idx >> 3, gl = idx & 7;
    int rg = tm * 192 + rr;
    if (rg > cnt - 1) rg = cnt - 1;
    int gg = gl ^ (rr & 7);
    asrc[c] = (unsigned)(off_e + rg) * 1536u + (unsigned)(gg * 16);
    adst[c] = (unsigned)(idx * 16);
  }
  const int brow = tid >> 3, bg8 = tid & 7;
  const unsigned bsrc = (unsigned)((td * 64 + brow) * 3072 + bg8 * 32);
  const unsigned bdst = (unsigned)(brow * 128 + ((bg8 ^ (brow & 7)) * 16));
  const char* bB = (const char*)wd + (size_t)e * D_DIM * F_DIM * 4;

  unsigned aRd[3];
#pragma unroll
  for (int fm = 0; fm < 3; ++fm) {
    int row = wm * 48 + fm * 16 + l15;
    aRd[fm] = (unsigned)(row * 128 + ((l4 ^ (row & 7)) * 16));
  }
  unsigned bRd[2];
#pragma unroll
  for (int fn = 0; fn < 2; ++fn) {
    int row = wn * 32 + fn * 16 + l15;
    bRd[fn] = (unsigned)(row * 128 + ((l4 ^ (row & 7)) * 16));
  }

  v4f zero = {0.f, 0.f, 0.f, 0.f};
  v4f acc[3][2];
#pragma unroll
  for (int fm = 0; fm < 3; ++fm)
#pragma unroll
    for (int fn = 0; fn < 2; ++fn) acc[fm][fn] = zero;

  auto COMPUTE = [&](unsigned ab, unsigned bb, unsigned sx) {
    v8bf af[3], bf_[2];
#pragma unroll
    for (int fm = 0; fm < 3; ++fm)
      af[fm] = __builtin_bit_cast(v8bf,
          *reinterpret_cast<const v8us*>(&lds[ab + (aRd[fm] ^ sx)]));
#pragma unroll
    for (int fn = 0; fn < 2; ++fn)
      bf_[fn] = __builtin_bit_cast(v8bf,
          *reinterpret_cast<const v8us*>(&lds[bb + (bRd[fn] ^ sx)]));
#pragma unroll
    for (int fm = 0; fm < 3; ++fm)
#pragma unroll
      for (int fn = 0; fn < 2; ++fn)
        acc[fm][fn] = __builtin_amdgcn_mfma_f32_16x16x32_bf16(af[fm], bf_[fn], acc[fm][fn], 0, 0, 0);
  };

  const int NG = F_DIM / 64;  // 12

  v4f b0 = gload4f(bB + bsrc);
  v4f b1 = gload4f(bB + bsrc + 16);
  SCHEDB();
#pragma unroll
  for (int c = 0; c < 3; ++c) gload16(hB + asrc[c], &lds[adst[c]]);
  SCHEDB();

#pragma unroll 2
  for (int i = 0; i < NG; ++i) {
    const unsigned ab = (unsigned)(i & 1) * 24576u;
    const unsigned bb = 49152u + (unsigned)(i & 1) * 8192u;
    VMWAIT(3); SCHEDB();   // B(i) x2 landed; A(i) x3 in flight
    *reinterpret_cast<v8us*>(&lds[bb + bdst]) = cvt8u(b0, b1);
    if (i + 1 < NG) {
      const unsigned an = (unsigned)((i + 1) & 1) * 24576u;
      unsigned bo = bsrc + (unsigned)(i + 1) * 256u;
      b0 = gload4f(bB + bo);
      b1 = gload4f(bB + bo + 16);
      SCHEDB();
      unsigned ao = (unsigned)(i + 1) * 128u;
#pragma unroll
      for (int c = 0; c < 3; ++c) gload16(hB + asrc[c] + ao, &lds[an + adst[c]]);
      SCHEDB();
      VMWAIT(5);   // queue [A(i)3, B(i+1)2, A(i+1)3] -> drain A(i)
    } else {
      VMWAIT(0);
    }
    SCHEDB(); LGKM0(); SBAR(); SCHEDB();
    COMPUTE(ab, bb, 0u);
    COMPUTE(ab, bb, 64u);
    SCHEDB(); SBAR();
  }

#pragma unroll
  for (int fm = 0; fm < 3; ++fm)
#pragma unroll
    for (int fn = 0; fn < 2; ++fn)
#pragma unroll
      for (int i = 0; i < 4; ++i) {
        int rloc = wm * 48 + fm * 16 + l4 * 4 + i;
        int rg = tm * 192 + rloc;
        if (rg < cnt) {
          int col = td * 64 + wn * 32 + fn * 16 + l15;
          float y = acc[fm][fn][i];
          if (STAGEOUT) {
            ybuf[(size_t)(off_e + rg) * D_DIM + col] = f2b(y);
          } else {
            int tok = tlist[e * T_TOK + rg];
            float w = wlist[e * T_TOK + rg];
            atomicAdd(out + (size_t)tok * D_DIM + col, w * y);
          }
        }
      }
}

// ---------------- Combine: out[t] = sum_k w_k * y[slot_k] ----------------
__global__ __launch_bounds__(256) void combine_kernel(
    const unsigned short* __restrict__ ybuf, const int* __restrict__ topk_e,
    const int* __restrict__ topk_p, const float* __restrict__ topk_w,
    const int* __restrict__ offsets, float* __restrict__ out)
{
  const int t = blockIdx.x, tid = threadIdx.x;
  const int d0 = tid * 8;
  float acc[8] = {0.f, 0.f, 0.f, 0.f, 0.f, 0.f, 0.f, 0.f};
#pragma unroll
  for (int k = 0; k < K_TOP; ++k) {
    int e = topk_e[t * K_TOP + k];
    int slot = offsets[e] + topk_p[t * K_TOP + k];
    float w = topk_w[t * K_TOP + k];
    v8us v = *reinterpret_cast<const v8us*>(ybuf + (size_t)slot * D_DIM + d0);
#pragma unroll
    for (int j = 0; j < 8; ++j) acc[j] += w * b2f(v[j]);
  }
  v4f o0 = {acc[0], acc[1], acc[2], acc[3]};
  v4f o1 = {acc[4], acc[5], acc[6], acc[7]};
  *reinterpret_cast<v4f*>(out + (size_t)t * D_DIM + d0) = o0;
  *reinterpret_cast<v4f*>(out + (size_t)t * D_DIM + d0 + 4) = o1;
}

extern "C" void kernel_launch(void* const* d_in, const int* in_sizes, int n_in,
                              void* d_out, int out_size, void* d_ws, size_t ws_size,
                              hipStream_t stream)
{
  const float* x  = (const float*)d_in[0];
  const float* gw = (const float*)d_in[1];
  const float* wg = (const float*)d_in[2];
  const float* wu = (const float*)d_in[3];
  const float* wd = (const float*)d_in[4];
  float* out = (float*)d_out;

  char* p = (char*)d_ws;
  auto alloc = [&](size_t bytes) {
    char* r = p;
    p += (bytes + 255) & ~(size_t)255;
    return r;
  };
  int* counts   = (int*)alloc(E_NUM * 4);
  int* offsets  = (int*)alloc(E_NUM * 4);
  int* tlist    = (int*)alloc((size_t)E_NUM * T_TOK * 4);
  float* wlist  = (float*)alloc((size_t)E_NUM * T_TOK * 4);
  int* topk_e   = (int*)alloc((size_t)T_TOK * K_TOP * 4);
  int* topk_p   = (int*)alloc((size_t)T_TOK * K_TOP * 4);
  float* topk_w = (float*)alloc((size_t)T_TOK * K_TOP * 4);
  unsigned short* xb   = (unsigned short*)alloc((size_t)T_TOK * D_DIM * 2);
  unsigned short* hbuf = (unsigned short*)alloc((size_t)T_TOK * K_TOP * F_DIM * 2);
  size_t need_atomic = (size_t)(p - (char*)d_ws);
  unsigned short* ybuf = (unsigned short*)alloc((size_t)T_TOK * K_TOP * D_DIM * 2);
  size_t need_stage = (size_t)(p - (char*)d_ws);

  if (ws_size < need_atomic) return;
  const bool stage = (ws_size >= need_stage);

  hipMemsetAsync(counts, 0, E_NUM * 4, stream);
  router_kernel<<<T_TOK, 256, 0, stream>>>(x, gw, xb, counts, tlist, topk_e, topk_p, topk_w, wlist);
  scan_kernel<<<1, 64, 0, stream>>>(counts, offsets);
  gateup_kernel<<<dim3(24 * E_NUM), 512, 0, stream>>>(
      xb, wg, wu, counts, offsets, tlist, hbuf);
  if (stage) {
    down_kernel<1><<<dim3(64 * E_NUM), 512, 0, stream>>>(
        hbuf, wd, counts, offsets, tlist, wlist, ybuf, out);
    combine_kernel<<<T_TOK, 256, 0, stream>>>(ybuf, topk_e, topk_p, topk_w, offsets, out);
  } else {
    hipMemsetAsync(out, 0, (size_t)out_size * 4, stream);
    down_kernel<0><<<dim3(64 * E_NUM), 512, 0, stream>>>(
        hbuf, wd, counts, offsets, tlist, wlist, ybuf, out);
  }
}